// Round 5
// baseline (14274.316 us; speedup 1.0000x reference)
//
#include <hip/hip_runtime.h>
#include <math.h>

// Problem constants
#define NB 32      // batch
#define TE 128     // encoder length
#define NT 64      // decoder steps
#define HH 1024    // hidden
#define EE 512     // embed dim
#define VV 32000   // vocab
#define GG 4096    // 4*H
#define WQN 5120   // Wa(1024) + W_hh(4096) output cols

typedef __attribute__((ext_vector_type(8))) short bh8;   // 8 bf16 (4 VGPRs)
typedef __attribute__((ext_vector_type(4))) float fx4;   // MFMA accumulator

__device__ __forceinline__ float tanh_fast(float x) {
  float e = __expf(2.f * x);
  return 1.f - 2.f / (e + 1.f);   // safe at +/-inf
}
__device__ __forceinline__ float sigf(float x) { return 1.f / (1.f + __expf(-x)); }
__device__ __forceinline__ ushort f2bf(float x) {  // RNE fp32 -> bf16 bits
  union { float f; unsigned u; } v; v.f = x;
  unsigned r = v.u + 0x7fffu + ((v.u >> 16) & 1u);
  return (ushort)(r >> 16);
}
__device__ __forceinline__ float bf2f(ushort u) {
  return __uint_as_float(((unsigned)u) << 16);
}

// h_bf <- bf16(encoder_hidden[0]), c_cur <- encoder_cell[0]
__global__ void k_init(const float* __restrict__ eh, const float* __restrict__ ec,
                       ushort* __restrict__ h_bf, float* __restrict__ c_cur) {
  int i = blockIdx.x * 256 + threadIdx.x;  // 32768
  h_bf[i] = f2bf(eh[i]);
  c_cur[i] = ec[i];
}

// emb_bf[t*NB+b][e] = bf16(emb_table[tok(t,b)][e]), padding_idx=0 -> 0, tok(0,b)=SOS=1
__global__ void k_emb(const int* __restrict__ tgt, const float* __restrict__ etab,
                      ushort* __restrict__ emb_bf) {
  int idx = blockIdx.x * 256 + threadIdx.x;  // NT*NB*EE = 1048576
  int e = idx & (EE - 1);
  int tb = idx >> 9;
  int b = tb & (NB - 1);
  int t = tb >> 5;
  int tok = (t == 0) ? 1 : tgt[b * NT + (t - 1)];
  emb_bf[idx] = (tok == 0) ? (ushort)0 : f2bf(etab[(size_t)tok * EE + e]);
}

// fp32 -> bf16, contiguous (n4 = count/4)
__global__ void k_f2b(const float* __restrict__ s, ushort* __restrict__ d, int n4) {
  int i = blockIdx.x * 256 + threadIdx.x;
  if (i >= n4) return;
  float4 v = *(const float4*)(s + (size_t)i * 4);
  *(ushort4*)(d + (size_t)i * 4) = make_ushort4(f2bf(v.x), f2bf(v.y), f2bf(v.z), f2bf(v.w));
}

// strided fp32 -> bf16: d[r][c] = bf16(s[r][off+c]), c < w4*4, dst ld = w4*4
__global__ void k_f2b_s(const float* __restrict__ s, int ld, int off, int w4,
                        ushort* __restrict__ d, int n) {
  int i = blockIdx.x * 256 + threadIdx.x;
  if (i >= n) return;
  int r = i / w4, c = (i - r * w4) * 4;
  float4 v = *(const float4*)(s + (size_t)r * ld + off + c);
  *(ushort4*)(d + (size_t)r * (w4 * 4) + c) = make_ushort4(f2bf(v.x), f2bf(v.y), f2bf(v.z), f2bf(v.w));
}

// ---- bf16 MFMA GEMM (m97 structure): 128x128 tile, BK=32, 4 waves 2x2.
// C[m][n] = sum_k A[m][k]*B[n][k] (+b1[n]+b2[n]); perm: out row = (m%32)*64 + m/32;
// obf: store bf16; swz: group 16 consecutive flat-bids onto one n-strip (m-tiles inner).
__device__ __forceinline__ void stage_pair(const ushort* A, int lda, const ushort* B, int ldb,
    int m0, int n0, int k0, ushort* ldsA, ushort* ldsB, int tid) {
  const int w = tid >> 6;
  const int row = tid >> 2;          // rows 0..63 (chunk 0), +64 (chunk 1)
  const int kq = (tid & 3) * 8;      // 8 bf16 = 16 B per lane
  const ushort* ga = A + (size_t)(m0 + row) * lda + k0 + kq;
  const ushort* gb = B + (size_t)(n0 + row) * ldb + k0 + kq;
  ushort* la = ldsA + w * 512;       // wave-uniform base; HW adds lane*16B
  ushort* lb = ldsB + w * 512;
  __builtin_amdgcn_global_load_lds((const __attribute__((address_space(1))) void*)ga,
      (__attribute__((address_space(3))) void*)la, 16, 0, 0);
  __builtin_amdgcn_global_load_lds((const __attribute__((address_space(1))) void*)(ga + (size_t)64 * lda),
      (__attribute__((address_space(3))) void*)(la + 2048), 16, 0, 0);
  __builtin_amdgcn_global_load_lds((const __attribute__((address_space(1))) void*)gb,
      (__attribute__((address_space(3))) void*)lb, 16, 0, 0);
  __builtin_amdgcn_global_load_lds((const __attribute__((address_space(1))) void*)(gb + (size_t)64 * ldb),
      (__attribute__((address_space(3))) void*)(lb + 2048), 16, 0, 0);
}

__global__ __launch_bounds__(256) void k_gemm_bf16(
    const ushort* __restrict__ A, int lda,
    const ushort* __restrict__ B, int ldb,
    const float* __restrict__ b1, const float* __restrict__ b2,
    void* __restrict__ Cv, int ldc, int K, int perm, int obf, int swz) {
  __shared__ ushort lds[2][2][4096];   // [buf][A/B][row*32+k], 32 KB
  const int tid = threadIdx.x;
  const int lane = tid & 63, w = tid >> 6;
  int m0, n0;
  if (swz) {
    const int bid = blockIdx.y * gridDim.x + blockIdx.x;
    m0 = (bid & 15) * 128;    // 16 m-tiles grouped per n-strip
    n0 = (bid >> 4) * 128;
  } else {
    m0 = blockIdx.y * 128;
    n0 = blockIdx.x * 128;
  }
  const int wm = (w >> 1) * 64, wn = (w & 1) * 64;
  fx4 acc[4][4] = {};
  stage_pair(A, lda, B, ldb, m0, n0, 0, lds[0][0], lds[0][1], tid);
  __syncthreads();
  const int nk = K >> 5;
  const int ko = (lane >> 4) * 8;        // frag k-offset
  const int rA = wm + (lane & 15);
  const int rB = wn + (lane & 15);
  for (int ks = 0; ks < nk; ++ks) {
    const int cur = ks & 1;
    if (ks + 1 < nk)
      stage_pair(A, lda, B, ldb, m0, n0, (ks + 1) << 5, lds[cur ^ 1][0], lds[cur ^ 1][1], tid);
    bh8 af[4], bfr[4];
#pragma unroll
    for (int f = 0; f < 4; ++f) {
      af[f]  = *(const bh8*)(&lds[cur][0][(rA + f * 16) * 32 + ko]);
      bfr[f] = *(const bh8*)(&lds[cur][1][(rB + f * 16) * 32 + ko]);
    }
#pragma unroll
    for (int i = 0; i < 4; ++i)
#pragma unroll
      for (int j = 0; j < 4; ++j)
        acc[i][j] = __builtin_amdgcn_mfma_f32_16x16x32_bf16(af[i], bfr[j], acc[i][j], 0, 0, 0);
    __syncthreads();
  }
  float* Cf = (float*)Cv;
  ushort* Cb = (ushort*)Cv;
#pragma unroll
  for (int j = 0; j < 4; ++j) {
    const int col = n0 + wn + j * 16 + (lane & 15);
    const float bv = (b1 ? b1[col] : 0.f) + (b2 ? b2[col] : 0.f);
#pragma unroll
    for (int i = 0; i < 4; ++i) {
      const int mb = m0 + wm + i * 16 + (lane >> 4) * 4;
#pragma unroll
      for (int r = 0; r < 4; ++r) {
        const int m = mb + r;
        const size_t orow = perm ? ((size_t)(m & 31) * 64 + (m >> 5)) : (size_t)m;
        const float v = acc[i][j][r] + bv;
        if (obf) Cb[orow * (size_t)ldc + col] = f2bf(v);
        else     Cf[orow * (size_t)ldc + col] = v;
      }
    }
  }
}

// ---- device-wide barrier (256 co-resident blocks; device-scope fences) ----
__device__ __forceinline__ void gridbar(unsigned* cnt, unsigned* gen) {
  __syncthreads();
  __threadfence();   // release: all prior stores visible device-wide
  if (threadIdx.x == 0) {
    unsigned g = __hip_atomic_load(gen, __ATOMIC_RELAXED, __HIP_MEMORY_SCOPE_AGENT);
    unsigned a = __hip_atomic_fetch_add(cnt, 1u, __ATOMIC_ACQ_REL, __HIP_MEMORY_SCOPE_AGENT);
    if (a == 255u) {
      __hip_atomic_store(cnt, 0u, __ATOMIC_RELAXED, __HIP_MEMORY_SCOPE_AGENT);
      __hip_atomic_store(gen, g + 1u, __ATOMIC_RELEASE, __HIP_MEMORY_SCOPE_AGENT);
    } else {
      while (__hip_atomic_load(gen, __ATOMIC_ACQUIRE, __HIP_MEMORY_SCOPE_AGENT) == g)
        __builtin_amdgcn_s_sleep(2);
    }
  }
  __syncthreads();
  __threadfence();   // acquire: subsequent loads see other blocks' stores
}

// ---- persistent recurrence kernel: all 64 steps, 3 phases/step ----
// grid = 256 blocks x 256 threads (co-resident: 1024 waves << 8192 capacity)
__global__ __launch_bounds__(256, 1) void k_recur(
    const ushort* __restrict__ Wqh,   // [5120][1024] bf16
    const ushort* __restrict__ encU,  // [32*128][1024] bf16
    const ushort* __restrict__ encW,  // [32*128][4096] bf16
    const float*  __restrict__ embG,  // [64*32][4096] f32
    const float*  __restrict__ Va,    // [1024]
    float* __restrict__ hWp,          // [4][32][5120] f32
    float* __restrict__ sc,           // [32][128]
    float* __restrict__ c_cur,        // [32][1024]
    ushort* __restrict__ h_bf,        // [32][1024] bf16
    ushort* __restrict__ hall,        // [64][32][1024] bf16
    unsigned* __restrict__ bar) {
  const int bid = blockIdx.x;
  const int tid = threadIdx.x;
  const int lane = tid & 63, w = tid >> 6;
  unsigned* cnt = bar;
  unsigned* gen = bar + 1;
  __shared__ float red[128], wt[TE], gp[4][128];

  for (int t = 0; t < NT; ++t) {
    // ---- phase 1: hWp[w][b][n] = h @ [Wa;W_hh]^T, k-split 4 (blocks 0..159) ----
    if (bid < 160) {
      const int n0 = bid * 32;
      const int kb = w * 256;
      const int r15 = lane & 15, ko = (lane >> 4) * 8;
      const ushort* A0 = h_bf + (size_t)r15 * HH + kb + ko;
      const ushort* A1 = A0 + 16 * HH;
      const ushort* B0 = Wqh + (size_t)(n0 + r15) * HH + kb + ko;
      const ushort* B1 = B0 + 16 * HH;
      fx4 a00 = {}, a01 = {}, a10 = {}, a11 = {};
#pragma unroll
      for (int ks = 0; ks < 8; ++ks) {
        const int k = ks * 32;
        bh8 av0 = *(const bh8*)(A0 + k), av1 = *(const bh8*)(A1 + k);
        bh8 bv0 = *(const bh8*)(B0 + k), bv1 = *(const bh8*)(B1 + k);
        a00 = __builtin_amdgcn_mfma_f32_16x16x32_bf16(av0, bv0, a00, 0, 0, 0);
        a01 = __builtin_amdgcn_mfma_f32_16x16x32_bf16(av0, bv1, a01, 0, 0, 0);
        a10 = __builtin_amdgcn_mfma_f32_16x16x32_bf16(av1, bv0, a10, 0, 0, 0);
        a11 = __builtin_amdgcn_mfma_f32_16x16x32_bf16(av1, bv1, a11, 0, 0, 0);
      }
      float* o = hWp + (size_t)w * (NB * WQN);
      const int rr = (lane >> 4) * 4;
#pragma unroll
      for (int r = 0; r < 4; ++r) {
        o[(size_t)(rr + r) * WQN + n0 + r15]           = a00[r];
        o[(size_t)(rr + r) * WQN + n0 + 16 + r15]      = a01[r];
        o[(size_t)(16 + rr + r) * WQN + n0 + r15]      = a10[r];
        o[(size_t)(16 + rr + r) * WQN + n0 + 16 + r15] = a11[r];
      }
    }
    gridbar(cnt, gen);

    // ---- phase 2: scores[b][t'] = sum_h tanh(q+encU)*Va ----
    {
      const int b = bid >> 3, tc = bid & 7;
      float qr[16], vr[16];
#pragma unroll
      for (int c = 0; c < 2; ++c) {
        const int h0 = c * 512 + lane * 8;
        float q[8] = {};
#pragma unroll
        for (int s2 = 0; s2 < 4; ++s2) {
          const float* hp = hWp + (size_t)s2 * (NB * WQN) + (size_t)b * WQN + h0;
          float4 pa = *(const float4*)hp;
          float4 pb = *(const float4*)(hp + 4);
          q[0] += pa.x; q[1] += pa.y; q[2] += pa.z; q[3] += pa.w;
          q[4] += pb.x; q[5] += pb.y; q[6] += pb.z; q[7] += pb.w;
        }
        float4 va = *(const float4*)(Va + h0);
        float4 vb = *(const float4*)(Va + h0 + 4);
#pragma unroll
        for (int j = 0; j < 8; ++j) qr[c * 8 + j] = q[j];
        vr[c*8+0] = va.x; vr[c*8+1] = va.y; vr[c*8+2] = va.z; vr[c*8+3] = va.w;
        vr[c*8+4] = vb.x; vr[c*8+5] = vb.y; vr[c*8+6] = vb.z; vr[c*8+7] = vb.w;
      }
#pragma unroll
      for (int it = 0; it < 4; ++it) {
        const int tt = tc * 16 + w * 4 + it;
        const ushort* ep = encU + (size_t)(b * TE + tt) * HH;
        float a = 0.f;
#pragma unroll
        for (int c = 0; c < 2; ++c) {
          bh8 e8 = *(const bh8*)(ep + c * 512 + lane * 8);
#pragma unroll
          for (int j = 0; j < 8; ++j)
            a += tanh_fast(qr[c * 8 + j] + bf2f((ushort)e8[j])) * vr[c * 8 + j];
        }
#pragma unroll
        for (int s2 = 32; s2 > 0; s2 >>= 1) a += __shfl_xor(a, s2);
        if (lane == 0) sc[b * TE + tt] = a;
      }
    }
    gridbar(cnt, gen);

    // ---- phase 3: softmax + gates (encW weighted sum) + LSTM pointwise ----
    {
      const int b = bid >> 3, u0 = (bid & 7) * 128;
      const float sv = (tid < TE) ? sc[b * TE + tid] : -1e30f;
      if (tid < 128) red[tid] = sv;
      __syncthreads();
      for (int st = 64; st > 0; st >>= 1) {
        if (tid < st) red[tid] = fmaxf(red[tid], red[tid + st]);
        __syncthreads();
      }
      const float mx = red[0];
      __syncthreads();
      const float ev = (tid < TE) ? __expf(sv - mx) : 0.f;
      if (tid < 128) { wt[tid] = ev; red[tid] = ev; }
      __syncthreads();
      for (int st = 64; st > 0; st >>= 1) {
        if (tid < st) red[tid] += red[tid + st];
        __syncthreads();
      }
      const float inv = 1.f / red[0];
      __syncthreads();
      // thread: gate g = tid>>6, unit pair ue
      const int g = tid >> 6, ue = (tid & 63) * 2;
      const int col = g * HH + u0 + ue;
      const ushort* base = encW + (size_t)(b * TE) * GG + col;
      float a0 = 0.f, a1 = 0.f;
#pragma unroll 8
      for (int tt = 0; tt < TE; ++tt) {
        ushort2 e2 = *(const ushort2*)(base + (size_t)tt * GG);
        const float wv = wt[tt];
        a0 += wv * bf2f(e2.x);
        a1 += wv * bf2f(e2.y);
      }
      a0 *= inv; a1 *= inv;
      float2 eg = *(const float2*)(embG + (size_t)(t * NB + b) * GG + col);
      a0 += eg.x; a1 += eg.y;
#pragma unroll
      for (int s2 = 0; s2 < 4; ++s2) {
        float2 hp = *(const float2*)(hWp + (size_t)s2 * (NB * WQN) + (size_t)b * WQN + HH + col);
        a0 += hp.x; a1 += hp.y;
      }
      gp[g][ue] = a0; gp[g][ue + 1] = a1;
      __syncthreads();
      if (tid < 128) {
        const float gi = gp[0][tid], gf = gp[1][tid], gg2 = gp[2][tid], go = gp[3][tid];
        const int idx = b * HH + u0 + tid;
        const float c = c_cur[idx];
        const float cn = sigf(gf) * c + sigf(gi) * tanh_fast(gg2);
        const float hn = sigf(go) * tanh_fast(cn);
        c_cur[idx] = cn;
        const ushort hb = f2bf(hn);
        h_bf[idx] = hb;
        hall[(size_t)t * (NB * HH) + idx] = hb;
      }
    }
    gridbar(cnt, gen);
  }
}

// Row-wise in-place log-softmax over V (one block per output row), float4
__global__ __launch_bounds__(256) void k_logsoftmax(float* __restrict__ out) {
  const size_t row = blockIdx.x;
  float* p = out + row * VV;
  __shared__ float sm[256], ss[256];
  const int tid = threadIdx.x;
  float m = -1e30f, s = 0.f;
  for (int i = tid; i < (VV / 4); i += 256) {
    float4 x = *(const float4*)(p + (size_t)i * 4);
    float m4 = fmaxf(fmaxf(x.x, x.y), fmaxf(x.z, x.w));
    float nm = fmaxf(m, m4);
    s = s * __expf(m - nm) + __expf(x.x - nm) + __expf(x.y - nm)
        + __expf(x.z - nm) + __expf(x.w - nm);
    m = nm;
  }
  sm[tid] = m; ss[tid] = s;
  __syncthreads();
  for (int st = 128; st > 0; st >>= 1) {
    if (tid < st) {
      float m2 = fmaxf(sm[tid], sm[tid + st]);
      ss[tid] = ss[tid] * __expf(sm[tid] - m2) + ss[tid + st] * __expf(sm[tid + st] - m2);
      sm[tid] = m2;
    }
    __syncthreads();
  }
  float L = sm[0] + logf(ss[0]);
  __syncthreads();
  for (int i = tid; i < (VV / 4); i += 256) {
    float4 x = *(const float4*)(p + (size_t)i * 4);
    x.x -= L; x.y -= L; x.z -= L; x.w -= L;
    *(float4*)(p + (size_t)i * 4) = x;
  }
}

extern "C" void kernel_launch(void* const* d_in, const int* in_sizes, int n_in,
                              void* d_out, int out_size, void* d_ws, size_t ws_size,
                              hipStream_t stream) {
  const float* enc   = (const float*)d_in[0];   // [32][128][1024]
  const float* ehid  = (const float*)d_in[1];   // [1][32][1024]
  const float* ecell = (const float*)d_in[2];
  const int*   tgt   = (const int*)d_in[3];     // [32][64]
  const float* etab  = (const float*)d_in[4];   // [32000][512]
  const float* Wa    = (const float*)d_in[5];   // [1024][1024]
  const float* Ua    = (const float*)d_in[6];
  const float* Va_w  = (const float*)d_in[7];   // [1][1024]
  // d_in[8] = Va_b: softmax-invariant constant, dropped
  const float* W_ih  = (const float*)d_in[9];   // [4096][1536]
  const float* W_hh  = (const float*)d_in[10];  // [4096][1024]
  const float* b_ih  = (const float*)d_in[11];
  const float* b_hh  = (const float*)d_in[12];
  const float* fc_w  = (const float*)d_in[13];  // [32000][1024]
  const float* fc_b  = (const float*)d_in[14];
  float* out = (float*)d_out;                   // [32][64][32000]
  float* ws = (float*)d_ws;

  // ---- workspace layout (float offsets), 115.34 MB total (same as R3) ----
  ushort* encW_bf = (ushort*)ws;                    // [4096][4096] bf16
  float*  embG    = ws + 8388608;                   // [2048][4096] f32
  ushort* fcw_bf  = (ushort*)ws;                    // [32000][1024] bf16 AFTER recurrence
  ushort* Wqh_bf  = (ushort*)(ws + 16777216);       // [5120][1024] bf16
  ushort* encU_bf = (ushort*)(ws + 19398656);       // [4096][1024] bf16
  // precompute scratch region [21495808 .. 27787264):
  ushort* enc_bf  = (ushort*)(ws + 21495808);       // [4096][1024] bf16
  ushort* Wihc_bf = (ushort*)(ws + 23592960);       // [4096][1024] bf16
  ushort* Ua_bf   = (ushort*)(ws + 25690112);       // [1024][1024]
  ushort* emb_bf  = (ushort*)(ws + 26214400);       // [2048][512]
  ushort* WihE_bf = (ushort*)(ws + 26738688);       // [4096][512]
  // recurrence overlays (all precompute scratch dead by then):
  float*  hWp     = ws + 21495808;                  // [4][32][5120] f32 (over enc_bf)
  float*  sc      = ws + 24117248;                  // [32][128]
  float*  c_cur   = ws + 24121344;                  // [32][1024]
  ushort* h_bf    = (ushort*)(ws + 24154112);       // [32][1024] bf16
  unsigned* bar   = (unsigned*)(ws + 27000000);     // {cnt, gen} (inside dead WihE region)
  ushort* hall_bf = (ushort*)(ws + 27787264);       // [64][32][1024] -> ends 28,835,840

  // ---- precompute ----
  k_emb<<<4096, 256, 0, stream>>>(tgt, etab, emb_bf);
  k_f2b<<<4096, 256, 0, stream>>>(enc, enc_bf, 1048576);
  k_f2b<<<1024, 256, 0, stream>>>(Ua, Ua_bf, 262144);
  k_f2b<<<1024, 256, 0, stream>>>(Wa, Wqh_bf, 262144);                      // rows 0..1023
  k_f2b<<<4096, 256, 0, stream>>>(W_hh, Wqh_bf + 1024 * HH, 1048576);       // rows 1024..5119
  k_f2b_s<<<4096, 256, 0, stream>>>(W_ih, 1536, 512, 256, Wihc_bf, 1048576);
  k_f2b_s<<<2048, 256, 0, stream>>>(W_ih, 1536, 0, 128, WihE_bf, 524288);
  // encU_bf = bf16(enc @ Ua^T): M=4096 N=1024 K=1024
  k_gemm_bf16<<<dim3(8, 32), 256, 0, stream>>>(enc_bf, HH, Ua_bf, HH, nullptr, nullptr,
                                               encU_bf, HH, HH, 0, 1, 0);
  // encW_bf = bf16(enc @ W_ih[:,512:]^T): M=4096 N=4096 K=1024
  k_gemm_bf16<<<dim3(32, 32), 256, 0, stream>>>(enc_bf, HH, Wihc_bf, HH, nullptr, nullptr,
                                                encW_bf, GG, HH, 0, 1, 0);
  // embG = emb @ W_ih[:,:512]^T + b_ih + b_hh: M=2048 N=4096 K=512 (f32 out)
  k_gemm_bf16<<<dim3(32, 16), 256, 0, stream>>>(emb_bf, EE, WihE_bf, EE, b_ih, b_hh,
                                                embG, GG, EE, 0, 0, 0);
  // barrier state + recurrence init (after the GEMMs that use overlaid regions)
  (void)hipMemsetAsync(bar, 0, 2 * sizeof(unsigned), stream);
  k_init<<<128, 256, 0, stream>>>(ehid, ecell, h_bf, c_cur);

  // ---- recurrence: ONE persistent kernel, 64 steps x 3 grid barriers ----
  k_recur<<<256, 256, 0, stream>>>(Wqh_bf, encU_bf, encW_bf, embG, Va_w,
                                   hWp, sc, c_cur, h_bf, hall_bf, bar);

  // ---- output projection + log-softmax ----
  k_f2b<<<32000, 256, 0, stream>>>(fc_w, fcw_bf, 8192000);
  k_gemm_bf16<<<dim3(250, 16), 256, 0, stream>>>(hall_bf, HH, fcw_bf, HH, fc_b, nullptr,
                                                 out, VV, HH, 1, 0, 1);
  k_logsoftmax<<<2048, 256, 0, stream>>>(out);
}

// Round 6
// 12776.102 us; speedup vs baseline: 1.1173x; 1.1173x over previous
//
#include <hip/hip_runtime.h>
#include <math.h>

// Problem constants
#define NB 32      // batch
#define TE 128     // encoder length
#define NT 64      // decoder steps
#define HH 1024    // hidden
#define EE 512     // embed dim
#define VV 32000   // vocab
#define GG 4096    // 4*H
#define WQN 5120   // Wa(1024) + W_hh(4096) output cols
#define NBLK 256   // persistent-kernel grid size

typedef __attribute__((ext_vector_type(8))) short bh8;   // 8 bf16 (4 VGPRs)
typedef __attribute__((ext_vector_type(4))) float fx4;   // MFMA accumulator

__device__ __forceinline__ float tanh_fast(float x) {
  float e = __expf(2.f * x);
  return 1.f - 2.f / (e + 1.f);   // safe at +/-inf
}
__device__ __forceinline__ float sigf(float x) { return 1.f / (1.f + __expf(-x)); }
__device__ __forceinline__ ushort f2bf(float x) {  // RNE fp32 -> bf16 bits
  union { float f; unsigned u; } v; v.f = x;
  unsigned r = v.u + 0x7fffu + ((v.u >> 16) & 1u);
  return (ushort)(r >> 16);
}
__device__ __forceinline__ float bf2f(ushort u) {
  return __uint_as_float(((unsigned)u) << 16);
}

// h_bf <- bf16(encoder_hidden[0]), c_cur <- encoder_cell[0]
__global__ void k_init(const float* __restrict__ eh, const float* __restrict__ ec,
                       ushort* __restrict__ h_bf, float* __restrict__ c_cur) {
  int i = blockIdx.x * 256 + threadIdx.x;  // 32768
  h_bf[i] = f2bf(eh[i]);
  c_cur[i] = ec[i];
}

// emb_bf[t*NB+b][e] = bf16(emb_table[tok(t,b)][e]), padding_idx=0 -> 0, tok(0,b)=SOS=1
__global__ void k_emb(const int* __restrict__ tgt, const float* __restrict__ etab,
                      ushort* __restrict__ emb_bf) {
  int idx = blockIdx.x * 256 + threadIdx.x;  // NT*NB*EE = 1048576
  int e = idx & (EE - 1);
  int tb = idx >> 9;
  int b = tb & (NB - 1);
  int t = tb >> 5;
  int tok = (t == 0) ? 1 : tgt[b * NT + (t - 1)];
  emb_bf[idx] = (tok == 0) ? (ushort)0 : f2bf(etab[(size_t)tok * EE + e]);
}

// fp32 -> bf16, contiguous (n4 = count/4)
__global__ void k_f2b(const float* __restrict__ s, ushort* __restrict__ d, int n4) {
  int i = blockIdx.x * 256 + threadIdx.x;
  if (i >= n4) return;
  float4 v = *(const float4*)(s + (size_t)i * 4);
  *(ushort4*)(d + (size_t)i * 4) = make_ushort4(f2bf(v.x), f2bf(v.y), f2bf(v.z), f2bf(v.w));
}

// strided fp32 -> bf16: d[r][c] = bf16(s[r][off+c]), c < w4*4, dst ld = w4*4
__global__ void k_f2b_s(const float* __restrict__ s, int ld, int off, int w4,
                        ushort* __restrict__ d, int n) {
  int i = blockIdx.x * 256 + threadIdx.x;
  if (i >= n) return;
  int r = i / w4, c = (i - r * w4) * 4;
  float4 v = *(const float4*)(s + (size_t)r * ld + off + c);
  *(ushort4*)(d + (size_t)r * (w4 * 4) + c) = make_ushort4(f2bf(v.x), f2bf(v.y), f2bf(v.z), f2bf(v.w));
}

// ---- bf16 MFMA GEMM (m97 structure): 128x128 tile, BK=32, 4 waves 2x2.
// C[m][n] = sum_k A[m][k]*B[n][k] (+b1[n]+b2[n]); perm: out row = (m%32)*64 + m/32;
// obf: store bf16; swz: group 16 consecutive flat-bids onto one n-strip (m-tiles inner).
__device__ __forceinline__ void stage_pair(const ushort* A, int lda, const ushort* B, int ldb,
    int m0, int n0, int k0, ushort* ldsA, ushort* ldsB, int tid) {
  const int w = tid >> 6;
  const int row = tid >> 2;          // rows 0..63 (chunk 0), +64 (chunk 1)
  const int kq = (tid & 3) * 8;      // 8 bf16 = 16 B per lane
  const ushort* ga = A + (size_t)(m0 + row) * lda + k0 + kq;
  const ushort* gb = B + (size_t)(n0 + row) * ldb + k0 + kq;
  ushort* la = ldsA + w * 512;       // wave-uniform base; HW adds lane*16B
  ushort* lb = ldsB + w * 512;
  __builtin_amdgcn_global_load_lds((const __attribute__((address_space(1))) void*)ga,
      (__attribute__((address_space(3))) void*)la, 16, 0, 0);
  __builtin_amdgcn_global_load_lds((const __attribute__((address_space(1))) void*)(ga + (size_t)64 * lda),
      (__attribute__((address_space(3))) void*)(la + 2048), 16, 0, 0);
  __builtin_amdgcn_global_load_lds((const __attribute__((address_space(1))) void*)gb,
      (__attribute__((address_space(3))) void*)lb, 16, 0, 0);
  __builtin_amdgcn_global_load_lds((const __attribute__((address_space(1))) void*)(gb + (size_t)64 * ldb),
      (__attribute__((address_space(3))) void*)(lb + 2048), 16, 0, 0);
}

__global__ __launch_bounds__(256) void k_gemm_bf16(
    const ushort* __restrict__ A, int lda,
    const ushort* __restrict__ B, int ldb,
    const float* __restrict__ b1, const float* __restrict__ b2,
    void* __restrict__ Cv, int ldc, int K, int perm, int obf, int swz) {
  __shared__ ushort lds[2][2][4096];   // [buf][A/B][row*32+k], 32 KB
  const int tid = threadIdx.x;
  const int lane = tid & 63, w = tid >> 6;
  int m0, n0;
  if (swz) {
    const int bid = blockIdx.y * gridDim.x + blockIdx.x;
    m0 = (bid & 15) * 128;    // 16 m-tiles grouped per n-strip
    n0 = (bid >> 4) * 128;
  } else {
    m0 = blockIdx.y * 128;
    n0 = blockIdx.x * 128;
  }
  const int wm = (w >> 1) * 64, wn = (w & 1) * 64;
  fx4 acc[4][4] = {};
  stage_pair(A, lda, B, ldb, m0, n0, 0, lds[0][0], lds[0][1], tid);
  __syncthreads();
  const int nk = K >> 5;
  const int ko = (lane >> 4) * 8;        // frag k-offset
  const int rA = wm + (lane & 15);
  const int rB = wn + (lane & 15);
  for (int ks = 0; ks < nk; ++ks) {
    const int cur = ks & 1;
    if (ks + 1 < nk)
      stage_pair(A, lda, B, ldb, m0, n0, (ks + 1) << 5, lds[cur ^ 1][0], lds[cur ^ 1][1], tid);
    bh8 af[4], bfr[4];
#pragma unroll
    for (int f = 0; f < 4; ++f) {
      af[f]  = *(const bh8*)(&lds[cur][0][(rA + f * 16) * 32 + ko]);
      bfr[f] = *(const bh8*)(&lds[cur][1][(rB + f * 16) * 32 + ko]);
    }
#pragma unroll
    for (int i = 0; i < 4; ++i)
#pragma unroll
      for (int j = 0; j < 4; ++j)
        acc[i][j] = __builtin_amdgcn_mfma_f32_16x16x32_bf16(af[i], bfr[j], acc[i][j], 0, 0, 0);
    __syncthreads();
  }
  float* Cf = (float*)Cv;
  ushort* Cb = (ushort*)Cv;
#pragma unroll
  for (int j = 0; j < 4; ++j) {
    const int col = n0 + wn + j * 16 + (lane & 15);
    const float bv = (b1 ? b1[col] : 0.f) + (b2 ? b2[col] : 0.f);
#pragma unroll
    for (int i = 0; i < 4; ++i) {
      const int mb = m0 + wm + i * 16 + (lane >> 4) * 4;
#pragma unroll
      for (int r = 0; r < 4; ++r) {
        const int m = mb + r;
        const size_t orow = perm ? ((size_t)(m & 31) * 64 + (m >> 5)) : (size_t)m;
        const float v = acc[i][j][r] + bv;
        if (obf) Cb[orow * (size_t)ldc + col] = f2bf(v);
        else     Cf[orow * (size_t)ldc + col] = v;
      }
    }
  }
}

// ---- contention-free device barrier ----
// Arrival: per-block flag (distinct 128B line) release-store — fully parallel.
// Block 0 wave 0 polls all flags, then release-stores gen = epoch.
// Others spin on gen. Epochs monotonic -> no reset races.
__device__ __forceinline__ void gridbar(unsigned* flags, unsigned* gen, unsigned epoch) {
  __syncthreads();
  __threadfence();   // release: phase stores visible device-wide
  const int tid = threadIdx.x;
  if (tid == 0)
    __hip_atomic_store(flags + blockIdx.x * 32, epoch, __ATOMIC_RELEASE, __HIP_MEMORY_SCOPE_AGENT);
  if (blockIdx.x == 0) {
    if (tid < 64) {
#pragma unroll
      for (int i = 0; i < NBLK / 64; ++i)
        while (__hip_atomic_load(flags + (i * 64 + tid) * 32, __ATOMIC_ACQUIRE,
                                 __HIP_MEMORY_SCOPE_AGENT) < epoch)
          __builtin_amdgcn_s_sleep(1);
    }
    __syncthreads();
    if (tid == 0)
      __hip_atomic_store(gen, epoch, __ATOMIC_RELEASE, __HIP_MEMORY_SCOPE_AGENT);
  } else if (tid == 0) {
    while (__hip_atomic_load(gen, __ATOMIC_ACQUIRE, __HIP_MEMORY_SCOPE_AGENT) < epoch)
      __builtin_amdgcn_s_sleep(1);
  }
  __syncthreads();
  __threadfence();   // acquire: see other blocks' stores
}

// ---- persistent recurrence kernel: all 64 steps, 3 phases/step ----
// grid = 256 blocks x 256 threads (co-resident: 1024 waves << 8192 capacity)
__global__ __launch_bounds__(256, 1) void k_recur(
    const ushort* __restrict__ Wqh,   // [5120][1024] bf16
    const ushort* __restrict__ encU,  // [32*128][1024] bf16
    const ushort* __restrict__ encW,  // [32*128][4096] bf16
    const float*  __restrict__ embG,  // [64*32][4096] f32
    const float*  __restrict__ Va,    // [1024]
    float* __restrict__ hWp,          // [4][32][5120] f32
    float* __restrict__ sc,           // [32][128]
    float* __restrict__ c_cur,        // [32][1024]
    ushort* __restrict__ h_bf,        // [32][1024] bf16
    ushort* __restrict__ hall,        // [64][32][1024] bf16
    unsigned* __restrict__ flags,     // [256*32] arrival flags
    unsigned* __restrict__ gen) {     // generation broadcast
  const int bid = blockIdx.x;
  const int tid = threadIdx.x;
  const int lane = tid & 63, w = tid >> 6;
  __shared__ float red[128], wt[TE], gp[4][128];
  unsigned epoch = 0;

  for (int t = 0; t < NT; ++t) {
    // ---- phase 1: hWp[w][b][n] = h @ [Wa;W_hh]^T, k-split 4 (blocks 0..159) ----
    if (bid < 160) {
      const int n0 = bid * 32;
      const int kb = w * 256;
      const int r15 = lane & 15, ko = (lane >> 4) * 8;
      const ushort* A0 = h_bf + (size_t)r15 * HH + kb + ko;
      const ushort* A1 = A0 + 16 * HH;
      const ushort* B0 = Wqh + (size_t)(n0 + r15) * HH + kb + ko;
      const ushort* B1 = B0 + 16 * HH;
      fx4 a00 = {}, a01 = {}, a10 = {}, a11 = {};
#pragma unroll
      for (int ks = 0; ks < 8; ++ks) {
        const int k = ks * 32;
        bh8 av0 = *(const bh8*)(A0 + k), av1 = *(const bh8*)(A1 + k);
        bh8 bv0 = *(const bh8*)(B0 + k), bv1 = *(const bh8*)(B1 + k);
        a00 = __builtin_amdgcn_mfma_f32_16x16x32_bf16(av0, bv0, a00, 0, 0, 0);
        a01 = __builtin_amdgcn_mfma_f32_16x16x32_bf16(av0, bv1, a01, 0, 0, 0);
        a10 = __builtin_amdgcn_mfma_f32_16x16x32_bf16(av1, bv0, a10, 0, 0, 0);
        a11 = __builtin_amdgcn_mfma_f32_16x16x32_bf16(av1, bv1, a11, 0, 0, 0);
      }
      float* o = hWp + (size_t)w * (NB * WQN);
      const int rr = (lane >> 4) * 4;
#pragma unroll
      for (int r = 0; r < 4; ++r) {
        o[(size_t)(rr + r) * WQN + n0 + r15]           = a00[r];
        o[(size_t)(rr + r) * WQN + n0 + 16 + r15]      = a01[r];
        o[(size_t)(16 + rr + r) * WQN + n0 + r15]      = a10[r];
        o[(size_t)(16 + rr + r) * WQN + n0 + 16 + r15] = a11[r];
      }
    }
    gridbar(flags, gen, ++epoch);

    // ---- phase 2: scores[b][t'] = sum_h tanh(q+encU)*Va ----
    {
      const int b = bid >> 3, tc = bid & 7;
      float qr[16], vr[16];
#pragma unroll
      for (int c = 0; c < 2; ++c) {
        const int h0 = c * 512 + lane * 8;
        float q[8] = {};
#pragma unroll
        for (int s2 = 0; s2 < 4; ++s2) {
          const float* hp = hWp + (size_t)s2 * (NB * WQN) + (size_t)b * WQN + h0;
          float4 pa = *(const float4*)hp;
          float4 pb = *(const float4*)(hp + 4);
          q[0] += pa.x; q[1] += pa.y; q[2] += pa.z; q[3] += pa.w;
          q[4] += pb.x; q[5] += pb.y; q[6] += pb.z; q[7] += pb.w;
        }
        float4 va = *(const float4*)(Va + h0);
        float4 vb = *(const float4*)(Va + h0 + 4);
#pragma unroll
        for (int j = 0; j < 8; ++j) qr[c * 8 + j] = q[j];
        vr[c*8+0] = va.x; vr[c*8+1] = va.y; vr[c*8+2] = va.z; vr[c*8+3] = va.w;
        vr[c*8+4] = vb.x; vr[c*8+5] = vb.y; vr[c*8+6] = vb.z; vr[c*8+7] = vb.w;
      }
#pragma unroll
      for (int it = 0; it < 4; ++it) {
        const int tt = tc * 16 + w * 4 + it;
        const ushort* ep = encU + (size_t)(b * TE + tt) * HH;
        float a = 0.f;
#pragma unroll
        for (int c = 0; c < 2; ++c) {
          bh8 e8 = *(const bh8*)(ep + c * 512 + lane * 8);
#pragma unroll
          for (int j = 0; j < 8; ++j)
            a += tanh_fast(qr[c * 8 + j] + bf2f((ushort)e8[j])) * vr[c * 8 + j];
        }
#pragma unroll
        for (int s2 = 32; s2 > 0; s2 >>= 1) a += __shfl_xor(a, s2);
        if (lane == 0) sc[b * TE + tt] = a;
      }
    }
    gridbar(flags, gen, ++epoch);

    // ---- phase 3: softmax + gates (encW weighted sum) + LSTM pointwise ----
    {
      const int b = bid >> 3, u0 = (bid & 7) * 128;
      const float sv = (tid < TE) ? sc[b * TE + tid] : -1e30f;
      if (tid < 128) red[tid] = sv;
      __syncthreads();
      for (int st = 64; st > 0; st >>= 1) {
        if (tid < st) red[tid] = fmaxf(red[tid], red[tid + st]);
        __syncthreads();
      }
      const float mx = red[0];
      __syncthreads();
      const float ev = (tid < TE) ? __expf(sv - mx) : 0.f;
      if (tid < 128) { wt[tid] = ev; red[tid] = ev; }
      __syncthreads();
      for (int st = 64; st > 0; st >>= 1) {
        if (tid < st) red[tid] += red[tid + st];
        __syncthreads();
      }
      const float inv = 1.f / red[0];
      __syncthreads();
      // thread: gate g = tid>>6, unit pair ue
      const int g = tid >> 6, ue = (tid & 63) * 2;
      const int col = g * HH + u0 + ue;
      const ushort* base = encW + (size_t)(b * TE) * GG + col;
      float a0 = 0.f, a1 = 0.f;
#pragma unroll 8
      for (int tt = 0; tt < TE; ++tt) {
        ushort2 e2 = *(const ushort2*)(base + (size_t)tt * GG);
        const float wv = wt[tt];
        a0 += wv * bf2f(e2.x);
        a1 += wv * bf2f(e2.y);
      }
      a0 *= inv; a1 *= inv;
      float2 eg = *(const float2*)(embG + (size_t)(t * NB + b) * GG + col);
      a0 += eg.x; a1 += eg.y;
#pragma unroll
      for (int s2 = 0; s2 < 4; ++s2) {
        float2 hp = *(const float2*)(hWp + (size_t)s2 * (NB * WQN) + (size_t)b * WQN + HH + col);
        a0 += hp.x; a1 += hp.y;
      }
      gp[g][ue] = a0; gp[g][ue + 1] = a1;
      __syncthreads();
      if (tid < 128) {
        const float gi = gp[0][tid], gf = gp[1][tid], gg2 = gp[2][tid], go = gp[3][tid];
        const int idx = b * HH + u0 + tid;
        const float c = c_cur[idx];
        const float cn = sigf(gf) * c + sigf(gi) * tanh_fast(gg2);
        const float hn = sigf(go) * tanh_fast(cn);
        c_cur[idx] = cn;
        const ushort hb = f2bf(hn);
        h_bf[idx] = hb;
        hall[(size_t)t * (NB * HH) + idx] = hb;
      }
    }
    gridbar(flags, gen, ++epoch);
  }
}

// Row-wise in-place log-softmax over V (one block per output row), float4
__global__ __launch_bounds__(256) void k_logsoftmax(float* __restrict__ out) {
  const size_t row = blockIdx.x;
  float* p = out + row * VV;
  __shared__ float sm[256], ss[256];
  const int tid = threadIdx.x;
  float m = -1e30f, s = 0.f;
  for (int i = tid; i < (VV / 4); i += 256) {
    float4 x = *(const float4*)(p + (size_t)i * 4);
    float m4 = fmaxf(fmaxf(x.x, x.y), fmaxf(x.z, x.w));
    float nm = fmaxf(m, m4);
    s = s * __expf(m - nm) + __expf(x.x - nm) + __expf(x.y - nm)
        + __expf(x.z - nm) + __expf(x.w - nm);
    m = nm;
  }
  sm[tid] = m; ss[tid] = s;
  __syncthreads();
  for (int st = 128; st > 0; st >>= 1) {
    if (tid < st) {
      float m2 = fmaxf(sm[tid], sm[tid + st]);
      ss[tid] = ss[tid] * __expf(sm[tid] - m2) + ss[tid + st] * __expf(sm[tid + st] - m2);
      sm[tid] = m2;
    }
    __syncthreads();
  }
  float L = sm[0] + logf(ss[0]);
  __syncthreads();
  for (int i = tid; i < (VV / 4); i += 256) {
    float4 x = *(const float4*)(p + (size_t)i * 4);
    x.x -= L; x.y -= L; x.z -= L; x.w -= L;
    *(float4*)(p + (size_t)i * 4) = x;
  }
}

extern "C" void kernel_launch(void* const* d_in, const int* in_sizes, int n_in,
                              void* d_out, int out_size, void* d_ws, size_t ws_size,
                              hipStream_t stream) {
  const float* enc   = (const float*)d_in[0];   // [32][128][1024]
  const float* ehid  = (const float*)d_in[1];   // [1][32][1024]
  const float* ecell = (const float*)d_in[2];
  const int*   tgt   = (const int*)d_in[3];     // [32][64]
  const float* etab  = (const float*)d_in[4];   // [32000][512]
  const float* Wa    = (const float*)d_in[5];   // [1024][1024]
  const float* Ua    = (const float*)d_in[6];
  const float* Va_w  = (const float*)d_in[7];   // [1][1024]
  // d_in[8] = Va_b: softmax-invariant constant, dropped
  const float* W_ih  = (const float*)d_in[9];   // [4096][1536]
  const float* W_hh  = (const float*)d_in[10];  // [4096][1024]
  const float* b_ih  = (const float*)d_in[11];
  const float* b_hh  = (const float*)d_in[12];
  const float* fc_w  = (const float*)d_in[13];  // [32000][1024]
  const float* fc_b  = (const float*)d_in[14];
  float* out = (float*)d_out;                   // [32][64][32000]
  float* ws = (float*)d_ws;

  // ---- workspace layout (float offsets), ~115.4 MB total ----
  ushort* encW_bf = (ushort*)ws;                    // [4096][4096] bf16
  float*  embG    = ws + 8388608;                   // [2048][4096] f32
  ushort* fcw_bf  = (ushort*)ws;                    // [32000][1024] bf16 AFTER recurrence
  ushort* Wqh_bf  = (ushort*)(ws + 16777216);       // [5120][1024] bf16
  ushort* encU_bf = (ushort*)(ws + 19398656);       // [4096][1024] bf16
  // precompute scratch region [21495808 .. 27787264):
  ushort* enc_bf  = (ushort*)(ws + 21495808);       // [4096][1024] bf16
  ushort* Wihc_bf = (ushort*)(ws + 23592960);       // [4096][1024] bf16
  ushort* Ua_bf   = (ushort*)(ws + 25690112);       // [1024][1024]
  ushort* emb_bf  = (ushort*)(ws + 26214400);       // [2048][512]
  ushort* WihE_bf = (ushort*)(ws + 26738688);       // [4096][512]
  // recurrence overlays (all precompute scratch dead by then):
  float*  hWp     = ws + 21495808;                  // [4][32][5120] f32 (over enc_bf)
  float*  sc      = ws + 24117248;                  // [32][128]
  float*  c_cur   = ws + 24121344;                  // [32][1024]
  ushort* h_bf    = (ushort*)(ws + 24154112);       // [32][1024] bf16
  unsigned* flags = (unsigned*)(ws + 27000000);     // [256*32] arrival flags (32 KB)
  unsigned* gen   = (unsigned*)(ws + 27008192);     // generation word
  ushort* hall_bf = (ushort*)(ws + 27787264);       // [64][32][1024] -> ends 28,835,840

  // ---- precompute ----
  k_emb<<<4096, 256, 0, stream>>>(tgt, etab, emb_bf);
  k_f2b<<<4096, 256, 0, stream>>>(enc, enc_bf, 1048576);
  k_f2b<<<1024, 256, 0, stream>>>(Ua, Ua_bf, 262144);
  k_f2b<<<1024, 256, 0, stream>>>(Wa, Wqh_bf, 262144);                      // rows 0..1023
  k_f2b<<<4096, 256, 0, stream>>>(W_hh, Wqh_bf + 1024 * HH, 1048576);       // rows 1024..5119
  k_f2b_s<<<4096, 256, 0, stream>>>(W_ih, 1536, 512, 256, Wihc_bf, 1048576);
  k_f2b_s<<<2048, 256, 0, stream>>>(W_ih, 1536, 0, 128, WihE_bf, 524288);
  // encU_bf = bf16(enc @ Ua^T): M=4096 N=1024 K=1024
  k_gemm_bf16<<<dim3(8, 32), 256, 0, stream>>>(enc_bf, HH, Ua_bf, HH, nullptr, nullptr,
                                               encU_bf, HH, HH, 0, 1, 0);
  // encW_bf = bf16(enc @ W_ih[:,512:]^T): M=4096 N=4096 K=1024
  k_gemm_bf16<<<dim3(32, 32), 256, 0, stream>>>(enc_bf, HH, Wihc_bf, HH, nullptr, nullptr,
                                                encW_bf, GG, HH, 0, 1, 0);
  // embG = emb @ W_ih[:,:512]^T + b_ih + b_hh: M=2048 N=4096 K=512 (f32 out)
  k_gemm_bf16<<<dim3(32, 16), 256, 0, stream>>>(emb_bf, EE, WihE_bf, EE, b_ih, b_hh,
                                                embG, GG, EE, 0, 0, 0);
  // barrier state + recurrence init (after the GEMMs that use overlaid regions)
  (void)hipMemsetAsync(flags, 0, (256 * 32 + 32) * sizeof(unsigned), stream);
  k_init<<<128, 256, 0, stream>>>(ehid, ecell, h_bf, c_cur);

  // ---- recurrence: ONE persistent kernel, 64 steps x 3 flag-barriers ----
  k_recur<<<NBLK, 256, 0, stream>>>(Wqh_bf, encU_bf, encW_bf, embG, Va_w,
                                    hWp, sc, c_cur, h_bf, hall_bf, flags, gen);

  // ---- output projection + log-softmax ----
  k_f2b<<<32000, 256, 0, stream>>>(fc_w, fcw_bf, 8192000);
  k_gemm_bf16<<<dim3(250, 16), 256, 0, stream>>>(hall_bf, HH, fcw_bf, HH, fc_b, nullptr,
                                                 out, VV, HH, 1, 0, 1);
  k_logsoftmax<<<2048, 256, 0, stream>>>(out);
}

// Round 7
// 2505.419 us; speedup vs baseline: 5.6974x; 5.0994x over previous
//
#include <hip/hip_runtime.h>
#include <math.h>

// Problem constants
#define NB 32      // batch
#define TE 128     // encoder length
#define NT 64      // decoder steps
#define HH 1024    // hidden
#define EE 512     // embed dim
#define VV 32000   // vocab
#define GG 4096    // 4*H
#define WQN 5120   // Wa(1024) + W_hh(4096) output cols
#define NBLK 256   // persistent-kernel grid size

typedef __attribute__((ext_vector_type(8))) short bh8;   // 8 bf16 (4 VGPRs)
typedef __attribute__((ext_vector_type(4))) float fx4;   // MFMA accumulator

__device__ __forceinline__ float tanh_fast(float x) {
  float e = __expf(2.f * x);
  return 1.f - 2.f / (e + 1.f);   // safe at +/-inf
}
__device__ __forceinline__ float sigf(float x) { return 1.f / (1.f + __expf(-x)); }
__device__ __forceinline__ ushort f2bf(float x) {  // RNE fp32 -> bf16 bits
  union { float f; unsigned u; } v; v.f = x;
  unsigned r = v.u + 0x7fffu + ((v.u >> 16) & 1u);
  return (ushort)(r >> 16);
}
__device__ __forceinline__ float bf2f(ushort u) {
  return __uint_as_float(((unsigned)u) << 16);
}

// agent-scope relaxed (coherent, fence-free) accessors
__device__ __forceinline__ void st_f32(float* p, float v) {
  __hip_atomic_store(p, v, __ATOMIC_RELAXED, __HIP_MEMORY_SCOPE_AGENT);
}
__device__ __forceinline__ float ld_f32(const float* p) {
  return __hip_atomic_load(p, __ATOMIC_RELAXED, __HIP_MEMORY_SCOPE_AGENT);
}
__device__ __forceinline__ void st_u32(unsigned* p, unsigned v) {
  __hip_atomic_store(p, v, __ATOMIC_RELAXED, __HIP_MEMORY_SCOPE_AGENT);
}
__device__ __forceinline__ unsigned ld_u32(const unsigned* p) {
  return __hip_atomic_load(p, __ATOMIC_RELAXED, __HIP_MEMORY_SCOPE_AGENT);
}

// h_u32 <- packed bf16 pairs of encoder_hidden[0]
__global__ void k_init(const float* __restrict__ eh, unsigned* __restrict__ h_u32) {
  int i = blockIdx.x * 256 + threadIdx.x;  // 16384
  float a = eh[i * 2], b = eh[i * 2 + 1];
  h_u32[i] = (unsigned)f2bf(a) | ((unsigned)f2bf(b) << 16);
}

// emb_bf[t*NB+b][e] = bf16(emb_table[tok(t,b)][e]), padding_idx=0 -> 0, tok(0,b)=SOS=1
__global__ void k_emb(const int* __restrict__ tgt, const float* __restrict__ etab,
                      ushort* __restrict__ emb_bf) {
  int idx = blockIdx.x * 256 + threadIdx.x;  // NT*NB*EE = 1048576
  int e = idx & (EE - 1);
  int tb = idx >> 9;
  int b = tb & (NB - 1);
  int t = tb >> 5;
  int tok = (t == 0) ? 1 : tgt[b * NT + (t - 1)];
  emb_bf[idx] = (tok == 0) ? (ushort)0 : f2bf(etab[(size_t)tok * EE + e]);
}

// fp32 -> bf16, contiguous (n4 = count/4)
__global__ void k_f2b(const float* __restrict__ s, ushort* __restrict__ d, int n4) {
  int i = blockIdx.x * 256 + threadIdx.x;
  if (i >= n4) return;
  float4 v = *(const float4*)(s + (size_t)i * 4);
  *(ushort4*)(d + (size_t)i * 4) = make_ushort4(f2bf(v.x), f2bf(v.y), f2bf(v.z), f2bf(v.w));
}

// strided fp32 -> bf16: d[r][c] = bf16(s[r][off+c]), c < w4*4, dst ld = w4*4
__global__ void k_f2b_s(const float* __restrict__ s, int ld, int off, int w4,
                        ushort* __restrict__ d, int n) {
  int i = blockIdx.x * 256 + threadIdx.x;
  if (i >= n) return;
  int r = i / w4, c = (i - r * w4) * 4;
  float4 v = *(const float4*)(s + (size_t)r * ld + off + c);
  *(ushort4*)(d + (size_t)r * (w4 * 4) + c) = make_ushort4(f2bf(v.x), f2bf(v.y), f2bf(v.z), f2bf(v.w));
}

// ---- bf16 MFMA GEMM (m97 structure): 128x128 tile, BK=32, 4 waves 2x2.
__device__ __forceinline__ void stage_pair(const ushort* A, int lda, const ushort* B, int ldb,
    int m0, int n0, int k0, ushort* ldsA, ushort* ldsB, int tid) {
  const int w = tid >> 6;
  const int row = tid >> 2;
  const int kq = (tid & 3) * 8;
  const ushort* ga = A + (size_t)(m0 + row) * lda + k0 + kq;
  const ushort* gb = B + (size_t)(n0 + row) * ldb + k0 + kq;
  ushort* la = ldsA + w * 512;
  ushort* lb = ldsB + w * 512;
  __builtin_amdgcn_global_load_lds((const __attribute__((address_space(1))) void*)ga,
      (__attribute__((address_space(3))) void*)la, 16, 0, 0);
  __builtin_amdgcn_global_load_lds((const __attribute__((address_space(1))) void*)(ga + (size_t)64 * lda),
      (__attribute__((address_space(3))) void*)(la + 2048), 16, 0, 0);
  __builtin_amdgcn_global_load_lds((const __attribute__((address_space(1))) void*)gb,
      (__attribute__((address_space(3))) void*)lb, 16, 0, 0);
  __builtin_amdgcn_global_load_lds((const __attribute__((address_space(1))) void*)(gb + (size_t)64 * ldb),
      (__attribute__((address_space(3))) void*)(lb + 2048), 16, 0, 0);
}

__global__ __launch_bounds__(256) void k_gemm_bf16(
    const ushort* __restrict__ A, int lda,
    const ushort* __restrict__ B, int ldb,
    const float* __restrict__ b1, const float* __restrict__ b2,
    void* __restrict__ Cv, int ldc, int K, int perm, int obf, int swz) {
  __shared__ ushort lds[2][2][4096];
  const int tid = threadIdx.x;
  const int lane = tid & 63, w = tid >> 6;
  int m0, n0;
  if (swz) {
    const int bid = blockIdx.y * gridDim.x + blockIdx.x;
    m0 = (bid & 15) * 128;
    n0 = (bid >> 4) * 128;
  } else {
    m0 = blockIdx.y * 128;
    n0 = blockIdx.x * 128;
  }
  const int wm = (w >> 1) * 64, wn = (w & 1) * 64;
  fx4 acc[4][4] = {};
  stage_pair(A, lda, B, ldb, m0, n0, 0, lds[0][0], lds[0][1], tid);
  __syncthreads();
  const int nk = K >> 5;
  const int ko = (lane >> 4) * 8;
  const int rA = wm + (lane & 15);
  const int rB = wn + (lane & 15);
  for (int ks = 0; ks < nk; ++ks) {
    const int cur = ks & 1;
    if (ks + 1 < nk)
      stage_pair(A, lda, B, ldb, m0, n0, (ks + 1) << 5, lds[cur ^ 1][0], lds[cur ^ 1][1], tid);
    bh8 af[4], bfr[4];
#pragma unroll
    for (int f = 0; f < 4; ++f) {
      af[f]  = *(const bh8*)(&lds[cur][0][(rA + f * 16) * 32 + ko]);
      bfr[f] = *(const bh8*)(&lds[cur][1][(rB + f * 16) * 32 + ko]);
    }
#pragma unroll
    for (int i = 0; i < 4; ++i)
#pragma unroll
      for (int j = 0; j < 4; ++j)
        acc[i][j] = __builtin_amdgcn_mfma_f32_16x16x32_bf16(af[i], bfr[j], acc[i][j], 0, 0, 0);
    __syncthreads();
  }
  float* Cf = (float*)Cv;
  ushort* Cb = (ushort*)Cv;
#pragma unroll
  for (int j = 0; j < 4; ++j) {
    const int col = n0 + wn + j * 16 + (lane & 15);
    const float bv = (b1 ? b1[col] : 0.f) + (b2 ? b2[col] : 0.f);
#pragma unroll
    for (int i = 0; i < 4; ++i) {
      const int mb = m0 + wm + i * 16 + (lane >> 4) * 4;
#pragma unroll
      for (int r = 0; r < 4; ++r) {
        const int m = mb + r;
        const size_t orow = perm ? ((size_t)(m & 31) * 64 + (m >> 5)) : (size_t)m;
        const float v = acc[i][j][r] + bv;
        if (obf) Cb[orow * (size_t)ldc + col] = f2bf(v);
        else     Cf[orow * (size_t)ldc + col] = v;
      }
    }
  }
}

// ---- fence-free device barrier: relaxed flags on distinct lines + gen broadcast.
// __syncthreads() drains vmcnt (HIP semantics) so data stores are at the
// coherence point before the flag store; data itself moves via agent-scope
// atomics, so no threadfence / L2 invalidation is needed.
__device__ __forceinline__ void gridbar(unsigned* flags, unsigned* gen, unsigned epoch) {
  __syncthreads();
  const int tid = threadIdx.x;
  if (tid == 0)
    st_u32(flags + blockIdx.x * 32, epoch);
  if (blockIdx.x == 0) {
    if (tid < 64) {
#pragma unroll
      for (int i = 0; i < NBLK / 64; ++i)
        while (ld_u32(flags + (i * 64 + tid) * 32) < epoch)
          __builtin_amdgcn_s_sleep(1);
    }
    __syncthreads();
    if (tid == 0) st_u32(gen, epoch);
  } else if (tid == 0) {
    while (ld_u32(gen) < epoch)
      __builtin_amdgcn_s_sleep(1);
  }
  __syncthreads();
}

// ---- persistent recurrence kernel: all 64 steps, 3 phases/step ----
// Cross-block data (hW, sc, h_u32) via agent-scope atomics only.
// c-state lives in registers (same block/thread owns it every step).
__global__ __launch_bounds__(256, 1) void k_recur(
    const ushort* __restrict__ Wqh,   // [5120][1024] bf16 (read-only, L2-cached)
    const ushort* __restrict__ encU,  // [32*128][1024] bf16
    const ushort* __restrict__ encW,  // [32*128][4096] bf16
    const float*  __restrict__ embG,  // [64*32][4096] f32
    const float*  __restrict__ Va,    // [1024]
    const float*  __restrict__ ec,    // [32*1024] encoder_cell
    float* __restrict__ hW,           // [32][5120] f32 (coherent)
    float* __restrict__ sc,           // [32][128] (coherent)
    unsigned* __restrict__ h_u32,     // [32][512] packed bf16 pairs (coherent)
    ushort* __restrict__ hall,        // [64][32][1024] bf16 (normal; flushed at kernel end)
    unsigned* __restrict__ flags, unsigned* __restrict__ gen) {
  const int bid = blockIdx.x;
  const int tid = threadIdx.x;
  const int lane = tid & 63, w = tid >> 6;
  __shared__ float wlds[4][32][33];            // phase-1 per-wave partials
  __shared__ float red[128], wt[TE], gp[4][128];
  unsigned epoch = 0;

  // phase-3 identity (constant across steps) + register-resident c state
  const int b3 = bid >> 3, u0 = (bid & 7) * 128;
  float c0r = 0.f, c1r = 0.f;
  if (tid < 64) {
    c0r = ec[b3 * HH + u0 + tid * 2];
    c1r = ec[b3 * HH + u0 + tid * 2 + 1];
  }

  for (int t = 0; t < NT; ++t) {
    // ---- phase 1: hW[b][n] = h @ [Wa;W_hh]^T (blocks 0..159, 32 n each;
    //      k-split 4 across waves, LDS-reduced -> single full result) ----
    if (bid < 160) {
      const int n0 = bid * 32;
      const int kb = w * 256;
      const int r15 = lane & 15, ko = (lane >> 4) * 8;
      const unsigned* h0p = h_u32 + r15 * 512 + (kb + ko) / 2;
      const unsigned* h1p = h0p + 16 * 512;
      const ushort* B0 = Wqh + (size_t)(n0 + r15) * HH + kb + ko;
      const ushort* B1 = B0 + 16 * HH;
      fx4 a00 = {}, a01 = {}, a10 = {}, a11 = {};
#pragma unroll
      for (int ks = 0; ks < 8; ++ks) {
        const int kofs = ks * 16;   // u32 units = 32 bf16
        union { unsigned u[4]; bh8 v; } A0u, A1u;
#pragma unroll
        for (int q = 0; q < 4; ++q) {
          A0u.u[q] = ld_u32(h0p + kofs + q);
          A1u.u[q] = ld_u32(h1p + kofs + q);
        }
        bh8 bv0 = *(const bh8*)(B0 + ks * 32);
        bh8 bv1 = *(const bh8*)(B1 + ks * 32);
        a00 = __builtin_amdgcn_mfma_f32_16x16x32_bf16(A0u.v, bv0, a00, 0, 0, 0);
        a01 = __builtin_amdgcn_mfma_f32_16x16x32_bf16(A0u.v, bv1, a01, 0, 0, 0);
        a10 = __builtin_amdgcn_mfma_f32_16x16x32_bf16(A1u.v, bv0, a10, 0, 0, 0);
        a11 = __builtin_amdgcn_mfma_f32_16x16x32_bf16(A1u.v, bv1, a11, 0, 0, 0);
      }
      const int rr = (lane >> 4) * 4;
#pragma unroll
      for (int r = 0; r < 4; ++r) {
        wlds[w][rr + r][r15]           = a00[r];
        wlds[w][rr + r][r15 + 16]      = a01[r];
        wlds[w][16 + rr + r][r15]      = a10[r];
        wlds[w][16 + rr + r][r15 + 16] = a11[r];
      }
      __syncthreads();
      const int row = tid >> 3, c0 = (tid & 7) * 4;
#pragma unroll
      for (int j = 0; j < 4; ++j) {
        float s = wlds[0][row][c0 + j] + wlds[1][row][c0 + j]
                + wlds[2][row][c0 + j] + wlds[3][row][c0 + j];
        st_f32(&hW[row * WQN + n0 + c0 + j], s);
      }
    }
    gridbar(flags, gen, ++epoch);

    // ---- phase 2: scores[b][t'] = sum_h tanh(q+encU)*Va ----
    {
      const int b = bid >> 3, tc = bid & 7;
      float qr[16], vr[16];
#pragma unroll
      for (int c = 0; c < 2; ++c) {
        const int h0 = c * 512 + lane * 8;
#pragma unroll
        for (int j = 0; j < 8; ++j) qr[c * 8 + j] = ld_f32(&hW[b * WQN + h0 + j]);
        float4 va = *(const float4*)(Va + h0);
        float4 vb = *(const float4*)(Va + h0 + 4);
        vr[c*8+0] = va.x; vr[c*8+1] = va.y; vr[c*8+2] = va.z; vr[c*8+3] = va.w;
        vr[c*8+4] = vb.x; vr[c*8+5] = vb.y; vr[c*8+6] = vb.z; vr[c*8+7] = vb.w;
      }
#pragma unroll
      for (int it = 0; it < 4; ++it) {
        const int tt = tc * 16 + w * 4 + it;
        const ushort* ep = encU + (size_t)(b * TE + tt) * HH;
        float a = 0.f;
#pragma unroll
        for (int c = 0; c < 2; ++c) {
          bh8 e8 = *(const bh8*)(ep + c * 512 + lane * 8);
#pragma unroll
          for (int j = 0; j < 8; ++j)
            a += tanh_fast(qr[c * 8 + j] + bf2f((ushort)e8[j])) * vr[c * 8 + j];
        }
#pragma unroll
        for (int s2 = 32; s2 > 0; s2 >>= 1) a += __shfl_xor(a, s2);
        if (lane == 0) st_f32(&sc[b * TE + tt], a);
      }
    }
    gridbar(flags, gen, ++epoch);

    // ---- phase 3: softmax + gates (encW weighted sum) + LSTM pointwise ----
    {
      const float sv = (tid < TE) ? ld_f32(&sc[b3 * TE + tid]) : -1e30f;
      if (tid < 128) red[tid] = sv;
      __syncthreads();
      for (int st = 64; st > 0; st >>= 1) {
        if (tid < st) red[tid] = fmaxf(red[tid], red[tid + st]);
        __syncthreads();
      }
      const float mx = red[0];
      __syncthreads();
      const float ev = (tid < TE) ? __expf(sv - mx) : 0.f;
      if (tid < 128) { wt[tid] = ev; red[tid] = ev; }
      __syncthreads();
      for (int st = 64; st > 0; st >>= 1) {
        if (tid < st) red[tid] += red[tid + st];
        __syncthreads();
      }
      const float inv = 1.f / red[0];
      __syncthreads();
      const int g = tid >> 6, ue = (tid & 63) * 2;
      const int col = g * HH + u0 + ue;
      const ushort* base = encW + (size_t)(b3 * TE) * GG + col;
      float a0 = 0.f, a1 = 0.f;
#pragma unroll 8
      for (int tt = 0; tt < TE; ++tt) {
        ushort2 e2 = *(const ushort2*)(base + (size_t)tt * GG);
        const float wv = wt[tt];
        a0 += wv * bf2f(e2.x);
        a1 += wv * bf2f(e2.y);
      }
      a0 *= inv; a1 *= inv;
      float2 eg = *(const float2*)(embG + (size_t)(t * NB + b3) * GG + col);
      a0 += eg.x + ld_f32(&hW[b3 * WQN + HH + col]);
      a1 += eg.y + ld_f32(&hW[b3 * WQN + HH + col + 1]);
      gp[g][ue] = a0; gp[g][ue + 1] = a1;
      __syncthreads();
      if (tid < 64) {
        const int e0 = tid * 2, e1 = tid * 2 + 1;
        const float cn0 = sigf(gp[1][e0]) * c0r + sigf(gp[0][e0]) * tanh_fast(gp[2][e0]);
        const float cn1 = sigf(gp[1][e1]) * c1r + sigf(gp[0][e1]) * tanh_fast(gp[2][e1]);
        c0r = cn0; c1r = cn1;
        const float hn0 = sigf(gp[3][e0]) * tanh_fast(cn0);
        const float hn1 = sigf(gp[3][e1]) * tanh_fast(cn1);
        const ushort hb0 = f2bf(hn0), hb1 = f2bf(hn1);
        st_u32(&h_u32[b3 * 512 + u0 / 2 + tid], (unsigned)hb0 | ((unsigned)hb1 << 16));
        *(ushort2*)(hall + (size_t)t * (NB * HH) + b3 * HH + u0 + e0) = make_ushort2(hb0, hb1);
      }
    }
    gridbar(flags, gen, ++epoch);
  }
}

// Row-wise in-place log-softmax over V (one block per output row), float4
__global__ __launch_bounds__(256) void k_logsoftmax(float* __restrict__ out) {
  const size_t row = blockIdx.x;
  float* p = out + row * VV;
  __shared__ float sm[256], ss[256];
  const int tid = threadIdx.x;
  float m = -1e30f, s = 0.f;
  for (int i = tid; i < (VV / 4); i += 256) {
    float4 x = *(const float4*)(p + (size_t)i * 4);
    float m4 = fmaxf(fmaxf(x.x, x.y), fmaxf(x.z, x.w));
    float nm = fmaxf(m, m4);
    s = s * __expf(m - nm) + __expf(x.x - nm) + __expf(x.y - nm)
        + __expf(x.z - nm) + __expf(x.w - nm);
    m = nm;
  }
  sm[tid] = m; ss[tid] = s;
  __syncthreads();
  for (int st = 128; st > 0; st >>= 1) {
    if (tid < st) {
      float m2 = fmaxf(sm[tid], sm[tid + st]);
      ss[tid] = ss[tid] * __expf(sm[tid] - m2) + ss[tid + st] * __expf(sm[tid + st] - m2);
      sm[tid] = m2;
    }
    __syncthreads();
  }
  float L = sm[0] + logf(ss[0]);
  __syncthreads();
  for (int i = tid; i < (VV / 4); i += 256) {
    float4 x = *(const float4*)(p + (size_t)i * 4);
    x.x -= L; x.y -= L; x.z -= L; x.w -= L;
    *(float4*)(p + (size_t)i * 4) = x;
  }
}

extern "C" void kernel_launch(void* const* d_in, const int* in_sizes, int n_in,
                              void* d_out, int out_size, void* d_ws, size_t ws_size,
                              hipStream_t stream) {
  const float* enc   = (const float*)d_in[0];   // [32][128][1024]
  const float* ehid  = (const float*)d_in[1];   // [1][32][1024]
  const float* ecell = (const float*)d_in[2];
  const int*   tgt   = (const int*)d_in[3];     // [32][64]
  const float* etab  = (const float*)d_in[4];   // [32000][512]
  const float* Wa    = (const float*)d_in[5];   // [1024][1024]
  const float* Ua    = (const float*)d_in[6];
  const float* Va_w  = (const float*)d_in[7];   // [1][1024]
  // d_in[8] = Va_b: softmax-invariant constant, dropped
  const float* W_ih  = (const float*)d_in[9];   // [4096][1536]
  const float* W_hh  = (const float*)d_in[10];  // [4096][1024]
  const float* b_ih  = (const float*)d_in[11];
  const float* b_hh  = (const float*)d_in[12];
  const float* fc_w  = (const float*)d_in[13];  // [32000][1024]
  const float* fc_b  = (const float*)d_in[14];
  float* out = (float*)d_out;                   // [32][64][32000]
  float* ws = (float*)d_ws;

  // ---- workspace layout (float offsets), ~115.4 MB total ----
  ushort* encW_bf = (ushort*)ws;                    // [4096][4096] bf16
  float*  embG    = ws + 8388608;                   // [2048][4096] f32
  ushort* fcw_bf  = (ushort*)ws;                    // [32000][1024] bf16 AFTER recurrence
  ushort* Wqh_bf  = (ushort*)(ws + 16777216);       // [5120][1024] bf16
  ushort* encU_bf = (ushort*)(ws + 19398656);       // [4096][1024] bf16
  // precompute scratch region [21495808 .. 27787264):
  ushort* enc_bf  = (ushort*)(ws + 21495808);       // [4096][1024] bf16
  ushort* Wihc_bf = (ushort*)(ws + 23592960);       // [4096][1024] bf16
  ushort* Ua_bf   = (ushort*)(ws + 25690112);       // [1024][1024]
  ushort* emb_bf  = (ushort*)(ws + 26214400);       // [2048][512]
  ushort* WihE_bf = (ushort*)(ws + 26738688);       // [4096][512]
  // recurrence overlays (precompute scratch dead by then):
  float*  hW      = ws + 21495808;                  // [32][5120] f32 coherent
  float*  sc      = ws + 21659648;                  // [32][128] coherent
  unsigned* h_u32 = (unsigned*)(ws + 21663744);     // [32][512] packed bf16 coherent
  unsigned* flags = (unsigned*)(ws + 27000000);     // [256*32] arrival flags
  unsigned* gen   = (unsigned*)(ws + 27008192);     // generation word
  ushort* hall_bf = (ushort*)(ws + 27787264);       // [64][32][1024] -> ends 28,835,840

  // ---- precompute ----
  k_emb<<<4096, 256, 0, stream>>>(tgt, etab, emb_bf);
  k_f2b<<<4096, 256, 0, stream>>>(enc, enc_bf, 1048576);
  k_f2b<<<1024, 256, 0, stream>>>(Ua, Ua_bf, 262144);
  k_f2b<<<1024, 256, 0, stream>>>(Wa, Wqh_bf, 262144);                      // rows 0..1023
  k_f2b<<<4096, 256, 0, stream>>>(W_hh, Wqh_bf + 1024 * HH, 1048576);       // rows 1024..5119
  k_f2b_s<<<4096, 256, 0, stream>>>(W_ih, 1536, 512, 256, Wihc_bf, 1048576);
  k_f2b_s<<<2048, 256, 0, stream>>>(W_ih, 1536, 0, 128, WihE_bf, 524288);
  // encU_bf = bf16(enc @ Ua^T): M=4096 N=1024 K=1024
  k_gemm_bf16<<<dim3(8, 32), 256, 0, stream>>>(enc_bf, HH, Ua_bf, HH, nullptr, nullptr,
                                               encU_bf, HH, HH, 0, 1, 0);
  // encW_bf = bf16(enc @ W_ih[:,512:]^T): M=4096 N=4096 K=1024
  k_gemm_bf16<<<dim3(32, 32), 256, 0, stream>>>(enc_bf, HH, Wihc_bf, HH, nullptr, nullptr,
                                                encW_bf, GG, HH, 0, 1, 0);
  // embG = emb @ W_ih[:,:512]^T + b_ih + b_hh: M=2048 N=4096 K=512 (f32 out)
  k_gemm_bf16<<<dim3(32, 16), 256, 0, stream>>>(emb_bf, EE, WihE_bf, EE, b_ih, b_hh,
                                                embG, GG, EE, 0, 0, 0);
  // barrier state + h init
  (void)hipMemsetAsync(flags, 0, (256 * 32 + 32) * sizeof(unsigned), stream);
  k_init<<<64, 256, 0, stream>>>(ehid, h_u32);

  // ---- recurrence: ONE persistent kernel, 64 steps x 3 fence-free barriers ----
  k_recur<<<NBLK, 256, 0, stream>>>(Wqh_bf, encU_bf, encW_bf, embG, Va_w, ecell,
                                    hW, sc, h_u32, hall_bf, flags, gen);

  // ---- output projection + log-softmax ----
  k_f2b<<<32000, 256, 0, stream>>>(fc_w, fcw_bf, 8192000);
  k_gemm_bf16<<<dim3(250, 16), 256, 0, stream>>>(hall_bf, HH, fcw_bf, HH, fc_b, nullptr,
                                                 out, VV, HH, 1, 0, 1);
  k_logsoftmax<<<2048, 256, 0, stream>>>(out);
}